// Round 1
// baseline (345.415 us; speedup 1.0000x reference)
//
#include <hip/hip_runtime.h>

typedef __bf16 bf16x8 __attribute__((ext_vector_type(8)));
typedef float floatx4 __attribute__((ext_vector_type(4)));

__device__ __forceinline__ unsigned short f2bf(float f) {
    union { float f; unsigned int u; } a;
    a.f = f;
    unsigned int u = a.u;
    unsigned int r = (u + 0x7FFFu + ((u >> 16) & 1u)) >> 16;  // RNE
    return (unsigned short)r;
}

__device__ __forceinline__ float bf2f(unsigned short s) {
    union { unsigned int u; float f; } a;
    a.u = ((unsigned int)s) << 16;
    return a.f;
}

__device__ __forceinline__ void async_copy16(const void* g, void* l) {
    __builtin_amdgcn_global_load_lds(
        (const __attribute__((address_space(1))) unsigned int*)g,
        (__attribute__((address_space(3))) unsigned int*)l,
        16, 0, 0);
}

// Concatenate two fp32 [rows,1024] matrices along columns into bf16 [rows,2048].
// One thread per 4 elements of the output.
__global__ void prep_cat_bf16(const float* __restrict__ a, const float* __restrict__ b,
                              unsigned short* __restrict__ out) {
    int t = blockIdx.x * 256 + threadIdx.x;
    size_t e = (size_t)t * 4;
    int m = (int)(e >> 11);
    int k = (int)(e & 2047);
    const float* src = (k < 1024) ? (a + (size_t)m * 1024 + k)
                                  : (b + (size_t)m * 1024 + (k - 1024));
    float4 v = *(const float4*)src;
    ushort4 o;
    o.x = f2bf(v.x); o.y = f2bf(v.y); o.z = f2bf(v.z); o.w = f2bf(v.w);
    *(ushort4*)(out + e) = o;
}

__global__ void prep_bias(const float* __restrict__ bx, const float* __restrict__ bh,
                          float* __restrict__ b) {
    int t = blockIdx.x * 256 + threadIdx.x;
    b[t] = bx[t] + bh[t];
}

// C = A @ W^T + bias, A [8192,2048] bf16, W [4096,2048] bf16, G [8192,4096] bf16.
// 128x128 tile, BK=32, 256 threads (4 waves, 2x2 of 64x64).
__global__ __launch_bounds__(256) void gemm_gates(
    const unsigned short* __restrict__ A,
    const unsigned short* __restrict__ W,
    const float* __restrict__ bias,
    unsigned short* __restrict__ G) {
    __shared__ __align__(16) char smem[16384];
    char* As = smem;           // 128 rows x 64 B (32 bf16), XOR-swizzled
    char* Bs = smem + 8192;

    const int t = threadIdx.x;
    const int lane = t & 63;
    const int wave = t >> 6;
    const int tileM = blockIdx.y * 128;
    const int tileN = blockIdx.x * 128;
    const int wm = wave & 1;
    const int wn = wave >> 1;
    const int l15 = lane & 15;
    const int quad = lane >> 4;

    floatx4 acc[4][4] = {};

    // staging indices: thread covers row lr (within 64-row block), 16B chunk lq
    const int lr = wave * 16 + (lane >> 2);
    const int lq = lane & 3;

    for (int kt = 0; kt < 2048; kt += 32) {
#pragma unroll
        for (int j = 0; j < 2; ++j) {
            int r = j * 64 + lr;
            int qg = lq ^ ((r >> 1) & 3);   // XOR swizzle: lds slot lq holds global chunk qg
            const unsigned short* ga = A + (size_t)(tileM + r) * 2048 + kt + qg * 8;
            async_copy16(ga, As + j * 4096 + wave * 1024);
            const unsigned short* gb = W + (size_t)(tileN + r) * 2048 + kt + qg * 8;
            async_copy16(gb, Bs + j * 4096 + wave * 1024);
        }
        __syncthreads();

        bf16x8 af[4], bf[4];
#pragma unroll
        for (int i = 0; i < 4; ++i) {
            int r = wm * 64 + i * 16 + l15;
            int qs = quad ^ ((r >> 1) & 3);
            af[i] = *(const bf16x8*)(As + r * 64 + qs * 16);
        }
#pragma unroll
        for (int j = 0; j < 4; ++j) {
            int r = wn * 64 + j * 16 + l15;
            int qs = quad ^ ((r >> 1) & 3);
            bf[j] = *(const bf16x8*)(Bs + r * 64 + qs * 16);
        }
#pragma unroll
        for (int i = 0; i < 4; ++i)
#pragma unroll
            for (int j = 0; j < 4; ++j)
                acc[i][j] = __builtin_amdgcn_mfma_f32_16x16x32_bf16(af[i], bf[j], acc[i][j], 0, 0, 0);
        __syncthreads();
    }

    // epilogue: C/D layout col = lane&15, row = quad*4 + reg
#pragma unroll
    for (int j = 0; j < 4; ++j) {
        int col = tileN + wn * 64 + j * 16 + l15;
        float bv = bias[col];
#pragma unroll
        for (int i = 0; i < 4; ++i) {
            int row0 = tileM + wm * 64 + i * 16 + quad * 4;
#pragma unroll
            for (int v = 0; v < 4; ++v) {
                G[(size_t)(row0 + v) * 4096 + col] = f2bf(acc[i][j][v] + bv);
            }
        }
    }
}

__device__ __forceinline__ void lstm_one(float gi, float gf, float go, float gc,
                                         float c1, float& hn, float& c) {
    float i = 1.f / (1.f + __expf(-gi));
    float f = 1.f / (1.f + __expf(-gf));
    float o = 1.f / (1.f + __expf(-go));
    float cb = tanhf(gc);
    c = 1.f / (1.f + __expf(-(f * c1 + i * cb)));   // reference quirk: sigmoid on cell
    hn = tanhf(c) * o;
}

// one thread per 4 (m,h) cells
__global__ void lstm_pointwise(const unsigned short* __restrict__ G,
                               const float* __restrict__ c1,
                               float* __restrict__ out) {
    int t = blockIdx.x * 256 + threadIdx.x;
    size_t e = (size_t)t * 4;
    int m = (int)(e >> 10);
    int h0 = (int)(e & 1023);
    const unsigned short* gr = G + (size_t)m * 4096 + h0;
    ushort4 vgi = *(const ushort4*)(gr);
    ushort4 vgf = *(const ushort4*)(gr + 1024);
    ushort4 vgo = *(const ushort4*)(gr + 2048);
    ushort4 vgc = *(const ushort4*)(gr + 3072);
    float4 vc1 = *(const float4*)(c1 + e);

    float4 hn, cc;
    lstm_one(bf2f(vgi.x), bf2f(vgf.x), bf2f(vgo.x), bf2f(vgc.x), vc1.x, hn.x, cc.x);
    lstm_one(bf2f(vgi.y), bf2f(vgf.y), bf2f(vgo.y), bf2f(vgc.y), vc1.y, hn.y, cc.y);
    lstm_one(bf2f(vgi.z), bf2f(vgf.z), bf2f(vgo.z), bf2f(vgc.z), vc1.z, hn.z, cc.z);
    lstm_one(bf2f(vgi.w), bf2f(vgf.w), bf2f(vgo.w), bf2f(vgc.w), vc1.w, hn.w, cc.w);

    *(float4*)(out + e) = hn;
    *(float4*)(out + 8388608 + e) = cc;   // second output: c, offset B*H
}

extern "C" void kernel_launch(void* const* d_in, const int* in_sizes, int n_in,
                              void* d_out, int out_size, void* d_ws, size_t ws_size,
                              hipStream_t stream) {
    const float* x  = (const float*)d_in[0];
    const float* h  = (const float*)d_in[1];
    const float* c1 = (const float*)d_in[2];
    const float* Wx = (const float*)d_in[3];
    const float* bx = (const float*)d_in[4];
    const float* Wh = (const float*)d_in[5];
    const float* bh = (const float*)d_in[6];
    float* out = (float*)d_out;

    char* ws = (char*)d_ws;
    unsigned short* Abf  = (unsigned short*)(ws);                // 33,554,432 B
    unsigned short* Wbf  = (unsigned short*)(ws + 33554432);     // 16,777,216 B
    float*          bias = (float*)(ws + 50331648);              //     16,384 B
    unsigned short* G    = (unsigned short*)(ws + 50348032);     // 67,108,864 B

    prep_cat_bf16<<<16384, 256, 0, stream>>>(x, h, Abf);
    prep_cat_bf16<<<8192, 256, 0, stream>>>(Wx, Wh, Wbf);
    prep_bias<<<16, 256, 0, stream>>>(bx, bh, bias);
    dim3 grid(32, 64);
    gemm_gates<<<grid, 256, 0, stream>>>(Abf, Wbf, bias, G);
    lstm_pointwise<<<8192, 256, 0, stream>>>(G, c1, out);
}